// Round 19
// baseline (65.545 us; speedup 1.0000x reference)
//
#include <hip/hip_runtime.h>
#include <hip/hip_bf16.h>

// MultiHeadAttention (additive/Bahdanau): B=2, Q=K=256, HIDDEN=1024, 8 heads x 128
// Pipeline:
//  1) prep:      split query/keys -> bf16 hi/lo; W^T*2log2e -> bf16 hi/lo (LDS transpose)
//  2) gemm_mfma: 3-term bf16 MFMA GEMMs; epilogue stores g = 2^(clamp(a,+-480)/4) (f32):
//                GQ [512][1024] (query side), GK [512][1024] (keys side, [k][d] layout —
//                R17 used d-major GKT; its 8 strided scalar prefetch loads + addr chains
//                cost ~5 extra inst/elem. [k][d] -> 2 dwordx4 w/ immediate offsets).
//  3) attn_fused (1024 blocks x 512 thr, q-tile 4): u = gq*gk; fminf(u,250); t = u^4 via
//     2 squarings. 4-way paired reciprocal (scalar): quad N/D, one rcp per 4 elems.
//     Waves: d-halves x k-quarters; d-partials via LDS; softmax waves 0-3; PV
//     row-pairs x k-quarters over 8 waves. launch_bounds(512,4): VGPR~56, no spill (R16!).

#define TANH_SCALE 2.88539008177792681472f   // 2*log2(e)
#define LOG2E      1.44269504088896340736f
#define UCLAMP     250.0f                    // t = u^4 <= 3.9e9; den <= 2.3e38 < f32max

typedef __attribute__((ext_vector_type(8))) short bf16x8_t;   // 8 bf16 = 4 VGPRs
typedef __attribute__((ext_vector_type(4))) float f32x4_t;

__device__ inline ushort bf16_rne(float f) {
  unsigned u = __float_as_uint(f);
  u += 0x7FFFu + ((u >> 16) & 1u);
  return (ushort)(u >> 16);
}
__device__ inline float bf16_to_f(ushort h) { return __uint_as_float((unsigned)h << 16); }
__device__ inline void split1(float v, ushort& hi, ushort& lo) {
  hi = bf16_rne(v);
  lo = bf16_rne(v - bf16_to_f(hi));
}

// ---------------- Kernel 1: prep (unchanged) ----------------
__global__ __launch_bounds__(256) void prep(
    const float* __restrict__ query, const float* __restrict__ keys,
    const float* __restrict__ Wq, const float* __restrict__ Wk,
    ushort* __restrict__ qhi, ushort* __restrict__ qlo,
    ushort* __restrict__ khi, ushort* __restrict__ klo,
    ushort* __restrict__ wqthi, ushort* __restrict__ wqtlo,
    ushort* __restrict__ wkthi, ushort* __restrict__ wktlo)
{
  __shared__ float t[64][65];
  const int bid = blockIdx.x, tid = threadIdx.x;
  if (bid < 1024) {
    const int z = bid >> 9;
    const float* in = z ? keys : query;
    ushort* hi = z ? khi : qhi;
    ushort* lo = z ? klo : qlo;
    const size_t i = ((size_t)(bid & 511) * 256 + tid) * 4;
    float4 v = *(const float4*)(in + i);
    ushort h0, h1, h2, h3, l0, l1, l2, l3;
    split1(v.x, h0, l0); split1(v.y, h1, l1);
    split1(v.z, h2, l2); split1(v.w, h3, l3);
    *(ushort4*)(hi + i) = make_ushort4(h0, h1, h2, h3);
    *(ushort4*)(lo + i) = make_ushort4(l0, l1, l2, l3);
  } else {
    const int idx = bid - 1024;
    const int z = idx >> 8;
    const float* W = z ? Wk : Wq;
    ushort* thi = z ? wkthi : wqthi;
    ushort* tlo = z ? wktlo : wqtlo;
    const int n0 = (idx & 15) * 64, h0 = ((idx >> 4) & 15) * 64;
    const int r = tid >> 4, c = (tid & 15) * 4;
#pragma unroll
    for (int i = 0; i < 4; ++i) {
      const int rr = r + i * 16;
      float4 wv = *(const float4*)(W + (size_t)(h0 + rr) * 1024 + n0 + c);
      t[rr][c + 0] = wv.x; t[rr][c + 1] = wv.y;
      t[rr][c + 2] = wv.z; t[rr][c + 3] = wv.w;
    }
    __syncthreads();
#pragma unroll
    for (int i = 0; i < 4; ++i) {
      const int rr = r + i * 16;
      ushort h0v, h1v, h2v, h3v, l0v, l1v, l2v, l3v;
      split1(t[c + 0][rr] * TANH_SCALE, h0v, l0v);
      split1(t[c + 1][rr] * TANH_SCALE, h1v, l1v);
      split1(t[c + 2][rr] * TANH_SCALE, h2v, l2v);
      split1(t[c + 3][rr] * TANH_SCALE, h3v, l3v);
      *(ushort4*)(thi + (size_t)(n0 + rr) * 1024 + h0 + c) = make_ushort4(h0v, h1v, h2v, h3v);
      *(ushort4*)(tlo + (size_t)(n0 + rr) * 1024 + h0 + c) = make_ushort4(l0v, l1v, l2v, l3v);
    }
  }
}

// ---------------- Kernel 2: MFMA GEMM, 3-term bf16 split; g = 2^(a/4) epilogue ----------------
// z=0: GQ = query@WqT; z=1: GK = keys@WkT. Identical geometry: [512][1024].
__global__ __launch_bounds__(256) void gemm_mfma(
    const ushort* __restrict__ qhi, const ushort* __restrict__ qlo,
    const ushort* __restrict__ khi, const ushort* __restrict__ klo,
    const ushort* __restrict__ wqthi, const ushort* __restrict__ wqtlo,
    const ushort* __restrict__ wkthi, const ushort* __restrict__ wktlo,
    float* __restrict__ GQ, float* __restrict__ GK)
{
  const int z = blockIdx.y;
  const int bid = blockIdx.x;
  const int m0 = (bid >> 4) * 64, n0 = (bid & 15) * 64;
  const ushort* Ah_g = z ? khi : qhi;
  const ushort* Al_g = z ? klo : qlo;
  const ushort* Bh_g = z ? wkthi : wqthi;
  const ushort* Bl_g = z ? wktlo : wqtlo;
  float* Gp = z ? GK : GQ;

  __shared__ __align__(16) ushort Ah[64 * 40];
  __shared__ __align__(16) ushort Al[64 * 40];
  __shared__ __align__(16) ushort Bh[64 * 40];
  __shared__ __align__(16) ushort Bl[64 * 40];

  const int tid = threadIdx.x;
  const int srow = tid >> 2, skc = (tid & 3) * 8;
  const size_t gA = (size_t)(m0 + srow) * 1024 + skc;
  const size_t gB = (size_t)(n0 + srow) * 1024 + skc;
  const int soff = srow * 40 + skc;

  uint4 rah = *(const uint4*)(Ah_g + gA);
  uint4 ral = *(const uint4*)(Al_g + gA);
  uint4 rbh = *(const uint4*)(Bh_g + gB);
  uint4 rbl = *(const uint4*)(Bl_g + gB);

  const int w = __builtin_amdgcn_readfirstlane(tid >> 6);
  const int lane = tid & 63;
  const int wm = (w >> 1) * 32, wn = (w & 1) * 32;
  const int fr = lane & 15, kg = lane >> 4;
  const int aoff = (wm + fr) * 40 + kg * 8;
  const int boff = (wn + fr) * 40 + kg * 8;

  f32x4_t acc[2][2] = {};

  for (int kk = 0; kk < 1024; kk += 32) {
    __syncthreads();
    *(uint4*)(Ah + soff) = rah;
    *(uint4*)(Al + soff) = ral;
    *(uint4*)(Bh + soff) = rbh;
    *(uint4*)(Bl + soff) = rbl;
    __syncthreads();

    if (kk + 32 < 1024) {
      rah = *(const uint4*)(Ah_g + gA + kk + 32);
      ral = *(const uint4*)(Al_g + gA + kk + 32);
      rbh = *(const uint4*)(Bh_g + gB + kk + 32);
      rbl = *(const uint4*)(Bl_g + gB + kk + 32);
    }

    bf16x8_t ah0 = *(const bf16x8_t*)(Ah + aoff);
    bf16x8_t ah1 = *(const bf16x8_t*)(Ah + aoff + 16 * 40);
    bf16x8_t al0 = *(const bf16x8_t*)(Al + aoff);
    bf16x8_t al1 = *(const bf16x8_t*)(Al + aoff + 16 * 40);
    bf16x8_t bh0 = *(const bf16x8_t*)(Bh + boff);
    bf16x8_t bh1 = *(const bf16x8_t*)(Bh + boff + 16 * 40);
    bf16x8_t bl0 = *(const bf16x8_t*)(Bl + boff);
    bf16x8_t bl1 = *(const bf16x8_t*)(Bl + boff + 16 * 40);

    acc[0][0] = __builtin_amdgcn_mfma_f32_16x16x32_bf16(ah0, bh0, acc[0][0], 0, 0, 0);
    acc[0][1] = __builtin_amdgcn_mfma_f32_16x16x32_bf16(ah0, bh1, acc[0][1], 0, 0, 0);
    acc[1][0] = __builtin_amdgcn_mfma_f32_16x16x32_bf16(ah1, bh0, acc[1][0], 0, 0, 0);
    acc[1][1] = __builtin_amdgcn_mfma_f32_16x16x32_bf16(ah1, bh1, acc[1][1], 0, 0, 0);
    acc[0][0] = __builtin_amdgcn_mfma_f32_16x16x32_bf16(ah0, bl0, acc[0][0], 0, 0, 0);
    acc[0][1] = __builtin_amdgcn_mfma_f32_16x16x32_bf16(ah0, bl1, acc[0][1], 0, 0, 0);
    acc[1][0] = __builtin_amdgcn_mfma_f32_16x16x32_bf16(ah1, bl0, acc[1][0], 0, 0, 0);
    acc[1][1] = __builtin_amdgcn_mfma_f32_16x16x32_bf16(ah1, bl1, acc[1][1], 0, 0, 0);
    acc[0][0] = __builtin_amdgcn_mfma_f32_16x16x32_bf16(al0, bh0, acc[0][0], 0, 0, 0);
    acc[0][1] = __builtin_amdgcn_mfma_f32_16x16x32_bf16(al0, bh1, acc[0][1], 0, 0, 0);
    acc[1][0] = __builtin_amdgcn_mfma_f32_16x16x32_bf16(al1, bh0, acc[1][0], 0, 0, 0);
    acc[1][1] = __builtin_amdgcn_mfma_f32_16x16x32_bf16(al1, bh1, acc[1][1], 0, 0, 0);
  }

#pragma unroll
  for (int fm = 0; fm < 2; ++fm)
#pragma unroll
    for (int fn = 0; fn < 2; ++fn) {
      const int col = n0 + wn + fn * 16 + fr;
#pragma unroll
      for (int j = 0; j < 4; ++j) {
        const int row = m0 + wm + fm * 16 + kg * 4 + j;
        float a = acc[fm][fn][j];
        a = fminf(fmaxf(a, -480.0f), 480.0f);
        Gp[(size_t)row * 1024 + col] = __builtin_amdgcn_exp2f(a * 0.25f);
      }
    }
}

// ---------------- Kernel 3: fused attn, [k][d] planes, 4-way paired rcp ----------------
// block = (b,h) = bid>>6, q-tile = (bid&63)*4. Wave w: d-half dh=w>>2, k-quarter kq=w&3,
// lane k = kq*64+lane. gk chunk = 2 dwordx4 contiguous (per-lane row). Quad N/D, 1 rcp/4.
__global__ __launch_bounds__(512, 4) void attn_fused(
    const float* __restrict__ GQ, const float* __restrict__ GK,
    const float* __restrict__ Va, const int* __restrict__ mask,
    const float* __restrict__ values,
    float* __restrict__ weights, float* __restrict__ ctx)
{
  __shared__ __align__(16) float gq_s[4][128];
  __shared__ __align__(16) float va_s[128];
  __shared__ __align__(16) float acc_lds[4][64][4];
  __shared__ float red_m[4][4];
  __shared__ float red_s[4][4];
  __shared__ __align__(16) float P_lds[4][256];
  __shared__ __align__(16) float4 pv_part[4][2][2][32];

  const int tid = threadIdx.x;
  const int lane = tid & 63;
  const int w = __builtin_amdgcn_readfirstlane(tid >> 6);
  const int bid = blockIdx.x;
  const int bh = bid >> 6;
  const int b = bh & 1, h = bh >> 1;
  const int qt = (bid & 63) * 4;
  const int dh = w >> 2, kq = w & 3;
  const int k = kq * 64 + lane;

  // stage gq tile (4x128) + Va head slice into LDS
  gq_s[tid >> 7][tid & 127] =
      GQ[(size_t)(b * 256 + qt + (tid >> 7)) * 1024 + h * 128 + (tid & 127)];
  if (tid < 32) *(float4*)&va_s[tid * 4] = *(const float4*)(Va + h * 128 + tid * 4);

  const float pen = 99.0f * (1.0f - (float)mask[b * 256 + k]);

  float ssum = Va[h * 128 + lane] + Va[h * 128 + 64 + lane];
#pragma unroll
  for (int off = 32; off; off >>= 1) ssum += __shfl_xor(ssum, off, 64);

  // per-lane contiguous gk row: [k][d] layout
  const float* gkp = GK + (size_t)(b * 256 + k) * 1024 + h * 128 + dh * 64;

  __syncthreads();

  float accA[4] = {0.f, 0.f, 0.f, 0.f};
  float accB[4] = {0.f, 0.f, 0.f, 0.f};

  float4 gkcA = *(const float4*)(gkp + 0);
  float4 gkcB = *(const float4*)(gkp + 4);

  for (int ch = 0; ch < 8; ++ch) {      // 8 chunks x 8 d = 64 d per wave
    const int d0 = ch * 8;
    float4 gknA, gknB;
    if (ch < 7) {                       // prefetch next chunk: 2 contiguous dwordx4
      gknA = *(const float4*)(gkp + d0 + 8);
      gknB = *(const float4*)(gkp + d0 + 12);
    }
    float va_[8];
    *(float4*)&va_[0] = *(const float4*)&va_s[dh * 64 + d0];
    *(float4*)&va_[4] = *(const float4*)&va_s[dh * 64 + d0 + 4];
    const float s01 = va_[0] + va_[1], s23 = va_[2] + va_[3];
    const float s45 = va_[4] + va_[5], s67 = va_[6] + va_[7];
#pragma unroll
    for (int q = 0; q < 4; ++q) {
      float4 A = *(const float4*)&gq_s[q][dh * 64 + d0];       // broadcast reads
      float4 Bv = *(const float4*)&gq_s[q][dh * 64 + d0 + 4];
      // quad A: d0..d3
      {
        float u0 = fminf(A.x * gkcA.x, UCLAMP);
        float u1 = fminf(A.y * gkcA.y, UCLAMP);
        float u2 = fminf(A.z * gkcA.z, UCLAMP);
        float u3 = fminf(A.w * gkcA.w, UCLAMP);
        u0 *= u0; u1 *= u1; u2 *= u2; u3 *= u3;
        const float t0 = u0 * u0, t1 = u1 * u1;
        const float t2 = u2 * u2, t3 = u3 * u3;
        const float p01 = fmaf(t0, t1, t0 + t1 + 1.0f);
        const float p23 = fmaf(t2, t3, t2 + t3 + 1.0f);
        const float den = p01 * p23;
        const float n01 = fmaf(va_[0], t1, fmaf(va_[1], t0, s01));
        const float n23 = fmaf(va_[2], t3, fmaf(va_[3], t2, s23));
        const float N = fmaf(n01, p23, n23 * p01);
        accA[q] = fmaf(N, __builtin_amdgcn_rcpf(den), accA[q]);
      }
      // quad B: d4..d7
      {
        float u0 = fminf(Bv.x * gkcB.x, UCLAMP);
        float u1 = fminf(Bv.y * gkcB.y, UCLAMP);
        float u2 = fminf(Bv.z * gkcB.z, UCLAMP);
        float u3 = fminf(Bv.w * gkcB.w, UCLAMP);
        u0 *= u0; u1 *= u1; u2 *= u2; u3 *= u3;
        const float t0 = u0 * u0, t1 = u1 * u1;
        const float t2 = u2 * u2, t3 = u3 * u3;
        const float p01 = fmaf(t0, t1, t0 + t1 + 1.0f);
        const float p23 = fmaf(t2, t3, t2 + t3 + 1.0f);
        const float den = p01 * p23;
        const float n01 = fmaf(va_[4], t1, fmaf(va_[5], t0, s45));
        const float n23 = fmaf(va_[6], t3, fmaf(va_[7], t2, s67));
        const float N = fmaf(n01, p23, n23 * p01);
        accB[q] = fmaf(N, __builtin_amdgcn_rcpf(den), accB[q]);
      }
    }
    if (ch < 7) { gkcA = gknA; gkcB = gknB; }
  }

  float acc[4];
#pragma unroll
  for (int q = 0; q < 4; ++q) acc[q] = accA[q] + accB[q];

  // combine d-halves: waves 4-7 export, waves 0-3 absorb
  if (w >= 4) {
#pragma unroll
    for (int q = 0; q < 4; ++q) acc_lds[kq][lane][q] = acc[q];
  }
  __syncthreads();

  float l[4], p[4];
  if (w < 4) {
#pragma unroll
    for (int q = 0; q < 4; ++q) {
      acc[q] += acc_lds[kq][lane][q];
      l[q] = ssum - 2.0f * acc[q] - pen;
    }
#pragma unroll
    for (int q = 0; q < 4; ++q) {
      float m = l[q];
#pragma unroll
      for (int off = 32; off; off >>= 1) m = fmaxf(m, __shfl_xor(m, off, 64));
      if (lane == 0) red_m[w][q] = m;
    }
  }
  __syncthreads();
  if (w < 4) {
#pragma unroll
    for (int q = 0; q < 4; ++q) {
      float m = fmaxf(fmaxf(red_m[0][q], red_m[1][q]), fmaxf(red_m[2][q], red_m[3][q]));
      p[q] = __builtin_amdgcn_exp2f((l[q] - m) * LOG2E);
    }
#pragma unroll
    for (int q = 0; q < 4; ++q) {
      float s = p[q];
#pragma unroll
      for (int off = 32; off; off >>= 1) s += __shfl_xor(s, off, 64);
      if (lane == 0) red_s[w][q] = s;
    }
  }
  __syncthreads();
  if (w < 4) {
#pragma unroll
    for (int q = 0; q < 4; ++q) {
      const float s = (red_s[0][q] + red_s[1][q]) + (red_s[2][q] + red_s[3][q]);
      const float pq = p[q] / s;
      weights[((size_t)((b * 8 + h) * 256) + qt + q) * 256 + k] = pq;
      P_lds[q][k] = pq;
    }
  }
  __syncthreads();

  // PV: wave w -> row pair rp = w&1 (rows 2rp, 2rp+1), k-quarter kq2 = w>>1.
  {
    const int rp = w & 1, kq2 = w >> 1;
    const int d4 = lane & 31, ks = lane >> 5;
    const int q0 = rp * 2, q1 = q0 + 1;
    const float* vb =
        values + (size_t)(b * 256 + kq2 * 64 + ks * 32) * 1024 + h * 128 + d4 * 4;
    const float* w0p = &P_lds[q0][kq2 * 64 + ks * 32];
    const float* w1p = &P_lds[q1][kq2 * 64 + ks * 32];
    float4 A0 = make_float4(0, 0, 0, 0), A1 = make_float4(0, 0, 0, 0);
#pragma unroll 4
    for (int j = 0; j < 32; ++j) {
      float4 v = *(const float4*)(vb + (size_t)j * 1024);
      const float pw0 = w0p[j], pw1 = w1p[j];
      A0.x += pw0 * v.x; A0.y += pw0 * v.y; A0.z += pw0 * v.z; A0.w += pw0 * v.w;
      A1.x += pw1 * v.x; A1.y += pw1 * v.y; A1.z += pw1 * v.z; A1.w += pw1 * v.w;
    }
    A0.x += __shfl_xor(A0.x, 32, 64); A0.y += __shfl_xor(A0.y, 32, 64);
    A0.z += __shfl_xor(A0.z, 32, 64); A0.w += __shfl_xor(A0.w, 32, 64);
    A1.x += __shfl_xor(A1.x, 32, 64); A1.y += __shfl_xor(A1.y, 32, 64);
    A1.z += __shfl_xor(A1.z, 32, 64); A1.w += __shfl_xor(A1.w, 32, 64);
    if (kq2 != 0 && lane < 32) {
      pv_part[kq2][rp][0][d4] = A0;
      pv_part[kq2][rp][1][d4] = A1;
    }
    __syncthreads();
    if (kq2 == 0 && lane < 32) {
#pragma unroll
      for (int s = 1; s < 4; ++s) {
        float4 pa = pv_part[s][rp][0][d4];
        float4 pb = pv_part[s][rp][1][d4];
        A0.x += pa.x; A0.y += pa.y; A0.z += pa.z; A0.w += pa.w;
        A1.x += pb.x; A1.y += pb.y; A1.z += pb.z; A1.w += pb.w;
      }
      *(float4*)&ctx[(size_t)(b * 256 + qt + q0) * 1024 + h * 128 + d4 * 4] = A0;
      *(float4*)&ctx[(size_t)(b * 256 + qt + q1) * 1024 + h * 128 + d4 * 4] = A1;
    }
  }
}

extern "C" void kernel_launch(void* const* d_in, const int* in_sizes, int n_in,
                              void* d_out, int out_size, void* d_ws, size_t ws_size,
                              hipStream_t stream) {
  const float* query  = (const float*)d_in[0];
  const float* keys   = (const float*)d_in[1];
  const float* values = (const float*)d_in[2];
  const int*   mask   = (const int*)d_in[3];
  const float* Wq     = (const float*)d_in[4];
  const float* Wk     = (const float*)d_in[5];
  const float* Va     = (const float*)d_in[6];

  float* ctx     = (float*)d_out;            // [2,256,1024]
  float* weights = ctx + 524288;             // [2,8,256,256]

  // ws layout (~16 MB used):
  ushort* qhi   = (ushort*)d_ws;             // 1 MB each
  ushort* qlo   = qhi + 524288;
  ushort* khi   = qlo + 524288;
  ushort* klo   = khi + 524288;
  ushort* wqthi = klo + 524288;              // 2 MB each
  ushort* wqtlo = wqthi + 1048576;
  ushort* wkthi = wqtlo + 1048576;
  ushort* wktlo = wkthi + 1048576;
  float*  GQ    = (float*)(wktlo + 1048576); // [512][1024] f32 (2 MB)
  float*  GK    = GQ + 524288;               // [512][1024] f32 (2 MB)

  prep<<<dim3(1536), 256, 0, stream>>>(query, keys, Wq, Wk,
                                       qhi, qlo, khi, klo,
                                       wqthi, wqtlo, wkthi, wktlo);
  gemm_mfma<<<dim3(128, 2), 256, 0, stream>>>(qhi, qlo, khi, klo,
                                              wqthi, wqtlo, wkthi, wktlo, GQ, GK);
  attn_fused<<<dim3(1024), 512, 0, stream>>>(GQ, GK, Va, mask, values, weights, ctx);
}

// Round 20
// 64.728 us; speedup vs baseline: 1.0126x; 1.0126x over previous
//
#include <hip/hip_runtime.h>
#include <hip/hip_bf16.h>

// MultiHeadAttention (additive/Bahdanau): B=2, Q=K=256, HIDDEN=1024, 8 heads x 128
// Pipeline:
//  1) prep:      split query/keys -> bf16 hi/lo; W^T*2log2e -> bf16 hi/lo (LDS transpose)
//  2) gemm_mfma: 3-term bf16 MFMA GEMMs; epilogue stores g = 2^(clamp(a,+-480)/4) (f32):
//                GQ [512][1024], GK [512][1024] (both [row][d]; per-lane contiguous loads).
//  3) attn_fused (1024 blocks x 512 thr, q-tile 4): u = gq*gk; fminf(u,15); t = u^4.
//     8-WAY paired reciprocal (R19): quad fractions combined before rcp ->
//     den8 = denA*denB <= (1+15^4)^8 = 4.3e37 < f32max; ONE rcp per 8 elements.
//     Clamp at u=15 <=> x=5.4 where tanh err <= 4e-5 (worst logit err ~0.004).
//     Waves: d-halves x k-quarters; d-partials via LDS; softmax waves 0-3; PV
//     row-pairs x k-quarters over 8 waves. launch_bounds(512,4): no spills (R16 lesson).

#define TANH_SCALE 2.88539008177792681472f   // 2*log2(e)
#define LOG2E      1.44269504088896340736f
#define UCLAMP     15.0f                     // t <= 50625; den8 <= 4.3e37 < f32max

typedef __attribute__((ext_vector_type(8))) short bf16x8_t;   // 8 bf16 = 4 VGPRs
typedef __attribute__((ext_vector_type(4))) float f32x4_t;

__device__ inline ushort bf16_rne(float f) {
  unsigned u = __float_as_uint(f);
  u += 0x7FFFu + ((u >> 16) & 1u);
  return (ushort)(u >> 16);
}
__device__ inline float bf16_to_f(ushort h) { return __uint_as_float((unsigned)h << 16); }
__device__ inline void split1(float v, ushort& hi, ushort& lo) {
  hi = bf16_rne(v);
  lo = bf16_rne(v - bf16_to_f(hi));
}

// ---------------- Kernel 1: prep (unchanged) ----------------
__global__ __launch_bounds__(256) void prep(
    const float* __restrict__ query, const float* __restrict__ keys,
    const float* __restrict__ Wq, const float* __restrict__ Wk,
    ushort* __restrict__ qhi, ushort* __restrict__ qlo,
    ushort* __restrict__ khi, ushort* __restrict__ klo,
    ushort* __restrict__ wqthi, ushort* __restrict__ wqtlo,
    ushort* __restrict__ wkthi, ushort* __restrict__ wktlo)
{
  __shared__ float t[64][65];
  const int bid = blockIdx.x, tid = threadIdx.x;
  if (bid < 1024) {
    const int z = bid >> 9;
    const float* in = z ? keys : query;
    ushort* hi = z ? khi : qhi;
    ushort* lo = z ? klo : qlo;
    const size_t i = ((size_t)(bid & 511) * 256 + tid) * 4;
    float4 v = *(const float4*)(in + i);
    ushort h0, h1, h2, h3, l0, l1, l2, l3;
    split1(v.x, h0, l0); split1(v.y, h1, l1);
    split1(v.z, h2, l2); split1(v.w, h3, l3);
    *(ushort4*)(hi + i) = make_ushort4(h0, h1, h2, h3);
    *(ushort4*)(lo + i) = make_ushort4(l0, l1, l2, l3);
  } else {
    const int idx = bid - 1024;
    const int z = idx >> 8;
    const float* W = z ? Wk : Wq;
    ushort* thi = z ? wkthi : wqthi;
    ushort* tlo = z ? wktlo : wqtlo;
    const int n0 = (idx & 15) * 64, h0 = ((idx >> 4) & 15) * 64;
    const int r = tid >> 4, c = (tid & 15) * 4;
#pragma unroll
    for (int i = 0; i < 4; ++i) {
      const int rr = r + i * 16;
      float4 wv = *(const float4*)(W + (size_t)(h0 + rr) * 1024 + n0 + c);
      t[rr][c + 0] = wv.x; t[rr][c + 1] = wv.y;
      t[rr][c + 2] = wv.z; t[rr][c + 3] = wv.w;
    }
    __syncthreads();
#pragma unroll
    for (int i = 0; i < 4; ++i) {
      const int rr = r + i * 16;
      ushort h0v, h1v, h2v, h3v, l0v, l1v, l2v, l3v;
      split1(t[c + 0][rr] * TANH_SCALE, h0v, l0v);
      split1(t[c + 1][rr] * TANH_SCALE, h1v, l1v);
      split1(t[c + 2][rr] * TANH_SCALE, h2v, l2v);
      split1(t[c + 3][rr] * TANH_SCALE, h3v, l3v);
      *(ushort4*)(thi + (size_t)(n0 + rr) * 1024 + h0 + c) = make_ushort4(h0v, h1v, h2v, h3v);
      *(ushort4*)(tlo + (size_t)(n0 + rr) * 1024 + h0 + c) = make_ushort4(l0v, l1v, l2v, l3v);
    }
  }
}

// ---------------- Kernel 2: MFMA GEMM, 3-term bf16 split; g = 2^(a/4) epilogue ----------------
// z=0: GQ = query@WqT; z=1: GK = keys@WkT. Identical geometry: [512][1024].
__global__ __launch_bounds__(256) void gemm_mfma(
    const ushort* __restrict__ qhi, const ushort* __restrict__ qlo,
    const ushort* __restrict__ khi, const ushort* __restrict__ klo,
    const ushort* __restrict__ wqthi, const ushort* __restrict__ wqtlo,
    const ushort* __restrict__ wkthi, const ushort* __restrict__ wktlo,
    float* __restrict__ GQ, float* __restrict__ GK)
{
  const int z = blockIdx.y;
  const int bid = blockIdx.x;
  const int m0 = (bid >> 4) * 64, n0 = (bid & 15) * 64;
  const ushort* Ah_g = z ? khi : qhi;
  const ushort* Al_g = z ? klo : qlo;
  const ushort* Bh_g = z ? wkthi : wqthi;
  const ushort* Bl_g = z ? wktlo : wqtlo;
  float* Gp = z ? GK : GQ;

  __shared__ __align__(16) ushort Ah[64 * 40];
  __shared__ __align__(16) ushort Al[64 * 40];
  __shared__ __align__(16) ushort Bh[64 * 40];
  __shared__ __align__(16) ushort Bl[64 * 40];

  const int tid = threadIdx.x;
  const int srow = tid >> 2, skc = (tid & 3) * 8;
  const size_t gA = (size_t)(m0 + srow) * 1024 + skc;
  const size_t gB = (size_t)(n0 + srow) * 1024 + skc;
  const int soff = srow * 40 + skc;

  uint4 rah = *(const uint4*)(Ah_g + gA);
  uint4 ral = *(const uint4*)(Al_g + gA);
  uint4 rbh = *(const uint4*)(Bh_g + gB);
  uint4 rbl = *(const uint4*)(Bl_g + gB);

  const int w = __builtin_amdgcn_readfirstlane(tid >> 6);
  const int lane = tid & 63;
  const int wm = (w >> 1) * 32, wn = (w & 1) * 32;
  const int fr = lane & 15, kg = lane >> 4;
  const int aoff = (wm + fr) * 40 + kg * 8;
  const int boff = (wn + fr) * 40 + kg * 8;

  f32x4_t acc[2][2] = {};

  for (int kk = 0; kk < 1024; kk += 32) {
    __syncthreads();
    *(uint4*)(Ah + soff) = rah;
    *(uint4*)(Al + soff) = ral;
    *(uint4*)(Bh + soff) = rbh;
    *(uint4*)(Bl + soff) = rbl;
    __syncthreads();

    if (kk + 32 < 1024) {
      rah = *(const uint4*)(Ah_g + gA + kk + 32);
      ral = *(const uint4*)(Al_g + gA + kk + 32);
      rbh = *(const uint4*)(Bh_g + gB + kk + 32);
      rbl = *(const uint4*)(Bl_g + gB + kk + 32);
    }

    bf16x8_t ah0 = *(const bf16x8_t*)(Ah + aoff);
    bf16x8_t ah1 = *(const bf16x8_t*)(Ah + aoff + 16 * 40);
    bf16x8_t al0 = *(const bf16x8_t*)(Al + aoff);
    bf16x8_t al1 = *(const bf16x8_t*)(Al + aoff + 16 * 40);
    bf16x8_t bh0 = *(const bf16x8_t*)(Bh + boff);
    bf16x8_t bh1 = *(const bf16x8_t*)(Bh + boff + 16 * 40);
    bf16x8_t bl0 = *(const bf16x8_t*)(Bl + boff);
    bf16x8_t bl1 = *(const bf16x8_t*)(Bl + boff + 16 * 40);

    acc[0][0] = __builtin_amdgcn_mfma_f32_16x16x32_bf16(ah0, bh0, acc[0][0], 0, 0, 0);
    acc[0][1] = __builtin_amdgcn_mfma_f32_16x16x32_bf16(ah0, bh1, acc[0][1], 0, 0, 0);
    acc[1][0] = __builtin_amdgcn_mfma_f32_16x16x32_bf16(ah1, bh0, acc[1][0], 0, 0, 0);
    acc[1][1] = __builtin_amdgcn_mfma_f32_16x16x32_bf16(ah1, bh1, acc[1][1], 0, 0, 0);
    acc[0][0] = __builtin_amdgcn_mfma_f32_16x16x32_bf16(ah0, bl0, acc[0][0], 0, 0, 0);
    acc[0][1] = __builtin_amdgcn_mfma_f32_16x16x32_bf16(ah0, bl1, acc[0][1], 0, 0, 0);
    acc[1][0] = __builtin_amdgcn_mfma_f32_16x16x32_bf16(ah1, bl0, acc[1][0], 0, 0, 0);
    acc[1][1] = __builtin_amdgcn_mfma_f32_16x16x32_bf16(ah1, bl1, acc[1][1], 0, 0, 0);
    acc[0][0] = __builtin_amdgcn_mfma_f32_16x16x32_bf16(al0, bh0, acc[0][0], 0, 0, 0);
    acc[0][1] = __builtin_amdgcn_mfma_f32_16x16x32_bf16(al0, bh1, acc[0][1], 0, 0, 0);
    acc[1][0] = __builtin_amdgcn_mfma_f32_16x16x32_bf16(al1, bh0, acc[1][0], 0, 0, 0);
    acc[1][1] = __builtin_amdgcn_mfma_f32_16x16x32_bf16(al1, bh1, acc[1][1], 0, 0, 0);
  }

#pragma unroll
  for (int fm = 0; fm < 2; ++fm)
#pragma unroll
    for (int fn = 0; fn < 2; ++fn) {
      const int col = n0 + wn + fn * 16 + fr;
#pragma unroll
      for (int j = 0; j < 4; ++j) {
        const int row = m0 + wm + fm * 16 + kg * 4 + j;
        float a = acc[fm][fn][j];
        a = fminf(fmaxf(a, -480.0f), 480.0f);
        Gp[(size_t)row * 1024 + col] = __builtin_amdgcn_exp2f(a * 0.25f);
      }
    }
}

// ---------------- Kernel 3: fused attn, 8-way paired rcp ----------------
// block = (b,h) = bid>>6, q-tile = (bid&63)*4. Wave w: d-half dh=w>>2, k-quarter kq=w&3,
// lane k = kq*64+lane. Per 8 elems: 2 quad fractions combined -> ONE rcp.
__global__ __launch_bounds__(512, 4) void attn_fused(
    const float* __restrict__ GQ, const float* __restrict__ GK,
    const float* __restrict__ Va, const int* __restrict__ mask,
    const float* __restrict__ values,
    float* __restrict__ weights, float* __restrict__ ctx)
{
  __shared__ __align__(16) float gq_s[4][128];
  __shared__ __align__(16) float va_s[128];
  __shared__ __align__(16) float acc_lds[4][64][4];
  __shared__ float red_m[4][4];
  __shared__ float red_s[4][4];
  __shared__ __align__(16) float P_lds[4][256];
  __shared__ __align__(16) float4 pv_part[4][2][2][32];

  const int tid = threadIdx.x;
  const int lane = tid & 63;
  const int w = __builtin_amdgcn_readfirstlane(tid >> 6);
  const int bid = blockIdx.x;
  const int bh = bid >> 6;
  const int b = bh & 1, h = bh >> 1;
  const int qt = (bid & 63) * 4;
  const int dh = w >> 2, kq = w & 3;
  const int k = kq * 64 + lane;

  // stage gq tile (4x128) + Va head slice into LDS
  gq_s[tid >> 7][tid & 127] =
      GQ[(size_t)(b * 256 + qt + (tid >> 7)) * 1024 + h * 128 + (tid & 127)];
  if (tid < 32) *(float4*)&va_s[tid * 4] = *(const float4*)(Va + h * 128 + tid * 4);

  const float pen = 99.0f * (1.0f - (float)mask[b * 256 + k]);

  float ssum = Va[h * 128 + lane] + Va[h * 128 + 64 + lane];
#pragma unroll
  for (int off = 32; off; off >>= 1) ssum += __shfl_xor(ssum, off, 64);

  // per-lane contiguous gk row: [k][d] layout
  const float* gkp = GK + (size_t)(b * 256 + k) * 1024 + h * 128 + dh * 64;

  __syncthreads();

  float acc[4] = {0.f, 0.f, 0.f, 0.f};

  float4 gkcA = *(const float4*)(gkp + 0);
  float4 gkcB = *(const float4*)(gkp + 4);

  for (int ch = 0; ch < 8; ++ch) {      // 8 chunks x 8 d = 64 d per wave
    const int d0 = ch * 8;
    float4 gknA, gknB;
    if (ch < 7) {                       // prefetch next chunk: 2 contiguous dwordx4
      gknA = *(const float4*)(gkp + d0 + 8);
      gknB = *(const float4*)(gkp + d0 + 12);
    }
    float va_[8];
    *(float4*)&va_[0] = *(const float4*)&va_s[dh * 64 + d0];
    *(float4*)&va_[4] = *(const float4*)&va_s[dh * 64 + d0 + 4];
    const float s01 = va_[0] + va_[1], s23 = va_[2] + va_[3];
    const float s45 = va_[4] + va_[5], s67 = va_[6] + va_[7];
#pragma unroll
    for (int q = 0; q < 4; ++q) {
      float4 A = *(const float4*)&gq_s[q][dh * 64 + d0];       // broadcast reads
      float4 Bv = *(const float4*)&gq_s[q][dh * 64 + d0 + 4];
      // quad A: d0..d3 -> NA/denA
      float u0 = fminf(A.x * gkcA.x, UCLAMP);
      float u1 = fminf(A.y * gkcA.y, UCLAMP);
      float u2 = fminf(A.z * gkcA.z, UCLAMP);
      float u3 = fminf(A.w * gkcA.w, UCLAMP);
      u0 *= u0; u1 *= u1; u2 *= u2; u3 *= u3;
      float t0 = u0 * u0, t1 = u1 * u1, t2 = u2 * u2, t3 = u3 * u3;
      float p01 = fmaf(t0, t1, t0 + t1 + 1.0f);
      float p23 = fmaf(t2, t3, t2 + t3 + 1.0f);
      const float denA = p01 * p23;
      float n01 = fmaf(va_[0], t1, fmaf(va_[1], t0, s01));
      float n23 = fmaf(va_[2], t3, fmaf(va_[3], t2, s23));
      const float NA = fmaf(n01, p23, n23 * p01);
      // quad B: d4..d7 -> NB/denB
      u0 = fminf(Bv.x * gkcB.x, UCLAMP);
      u1 = fminf(Bv.y * gkcB.y, UCLAMP);
      u2 = fminf(Bv.z * gkcB.z, UCLAMP);
      u3 = fminf(Bv.w * gkcB.w, UCLAMP);
      u0 *= u0; u1 *= u1; u2 *= u2; u3 *= u3;
      t0 = u0 * u0; t1 = u1 * u1; t2 = u2 * u2; t3 = u3 * u3;
      p01 = fmaf(t0, t1, t0 + t1 + 1.0f);
      p23 = fmaf(t2, t3, t2 + t3 + 1.0f);
      const float denB = p01 * p23;
      n01 = fmaf(va_[4], t1, fmaf(va_[5], t0, s45));
      n23 = fmaf(va_[6], t3, fmaf(va_[7], t2, s67));
      const float NB = fmaf(n01, p23, n23 * p01);
      // 8-way combine: one rcp
      const float den8 = denA * denB;                 // <= 4.3e37, finite
      const float N8 = fmaf(NA, denB, NB * denA);
      acc[q] = fmaf(N8, __builtin_amdgcn_rcpf(den8), acc[q]);
    }
    if (ch < 7) { gkcA = gknA; gkcB = gknB; }
  }

  // combine d-halves: waves 4-7 export, waves 0-3 absorb
  if (w >= 4) {
#pragma unroll
    for (int q = 0; q < 4; ++q) acc_lds[kq][lane][q] = acc[q];
  }
  __syncthreads();

  float l[4], p[4];
  if (w < 4) {
#pragma unroll
    for (int q = 0; q < 4; ++q) {
      acc[q] += acc_lds[kq][lane][q];
      l[q] = ssum - 2.0f * acc[q] - pen;
    }
#pragma unroll
    for (int q = 0; q < 4; ++q) {
      float m = l[q];
#pragma unroll
      for (int off = 32; off; off >>= 1) m = fmaxf(m, __shfl_xor(m, off, 64));
      if (lane == 0) red_m[w][q] = m;
    }
  }
  __syncthreads();
  if (w < 4) {
#pragma unroll
    for (int q = 0; q < 4; ++q) {
      float m = fmaxf(fmaxf(red_m[0][q], red_m[1][q]), fmaxf(red_m[2][q], red_m[3][q]));
      p[q] = __builtin_amdgcn_exp2f((l[q] - m) * LOG2E);
    }
#pragma unroll
    for (int q = 0; q < 4; ++q) {
      float s = p[q];
#pragma unroll
      for (int off = 32; off; off >>= 1) s += __shfl_xor(s, off, 64);
      if (lane == 0) red_s[w][q] = s;
    }
  }
  __syncthreads();
  if (w < 4) {
#pragma unroll
    for (int q = 0; q < 4; ++q) {
      const float s = (red_s[0][q] + red_s[1][q]) + (red_s[2][q] + red_s[3][q]);
      const float pq = p[q] / s;
      weights[((size_t)((b * 8 + h) * 256) + qt + q) * 256 + k] = pq;
      P_lds[q][k] = pq;
    }
  }
  __syncthreads();

  // PV: wave w -> row pair rp = w&1 (rows 2rp, 2rp+1), k-quarter kq2 = w>>1.
  {
    const int rp = w & 1, kq2 = w >> 1;
    const int d4 = lane & 31, ks = lane >> 5;
    const int q0 = rp * 2, q1 = q0 + 1;
    const float* vb =
        values + (size_t)(b * 256 + kq2 * 64 + ks * 32) * 1024 + h * 128 + d4 * 4;
    const float* w0p = &P_lds[q0][kq2 * 64 + ks * 32];
    const float* w1p = &P_lds[q1][kq2 * 64 + ks * 32];
    float4 A0 = make_float4(0, 0, 0, 0), A1 = make_float4(0, 0, 0, 0);
#pragma unroll 4
    for (int j = 0; j < 32; ++j) {
      float4 v = *(const float4*)(vb + (size_t)j * 1024);
      const float pw0 = w0p[j], pw1 = w1p[j];
      A0.x += pw0 * v.x; A0.y += pw0 * v.y; A0.z += pw0 * v.z; A0.w += pw0 * v.w;
      A1.x += pw1 * v.x; A1.y += pw1 * v.y; A1.z += pw1 * v.z; A1.w += pw1 * v.w;
    }
    A0.x += __shfl_xor(A0.x, 32, 64); A0.y += __shfl_xor(A0.y, 32, 64);
    A0.z += __shfl_xor(A0.z, 32, 64); A0.w += __shfl_xor(A0.w, 32, 64);
    A1.x += __shfl_xor(A1.x, 32, 64); A1.y += __shfl_xor(A1.y, 32, 64);
    A1.z += __shfl_xor(A1.z, 32, 64); A1.w += __shfl_xor(A1.w, 32, 64);
    if (kq2 != 0 && lane < 32) {
      pv_part[kq2][rp][0][d4] = A0;
      pv_part[kq2][rp][1][d4] = A1;
    }
    __syncthreads();
    if (kq2 == 0 && lane < 32) {
#pragma unroll
      for (int s = 1; s < 4; ++s) {
        float4 pa = pv_part[s][rp][0][d4];
        float4 pb = pv_part[s][rp][1][d4];
        A0.x += pa.x; A0.y += pa.y; A0.z += pa.z; A0.w += pa.w;
        A1.x += pb.x; A1.y += pb.y; A1.z += pb.z; A1.w += pb.w;
      }
      *(float4*)&ctx[(size_t)(b * 256 + qt + q0) * 1024 + h * 128 + d4 * 4] = A0;
      *(float4*)&ctx[(size_t)(b * 256 + qt + q1) * 1024 + h * 128 + d4 * 4] = A1;
    }
  }
}

extern "C" void kernel_launch(void* const* d_in, const int* in_sizes, int n_in,
                              void* d_out, int out_size, void* d_ws, size_t ws_size,
                              hipStream_t stream) {
  const float* query  = (const float*)d_in[0];
  const float* keys   = (const float*)d_in[1];
  const float* values = (const float*)d_in[2];
  const int*   mask   = (const int*)d_in[3];
  const float* Wq     = (const float*)d_in[4];
  const float* Wk     = (const float*)d_in[5];
  const float* Va     = (const float*)d_in[6];

  float* ctx     = (float*)d_out;            // [2,256,1024]
  float* weights = ctx + 524288;             // [2,8,256,256]

  // ws layout (~16 MB used):
  ushort* qhi   = (ushort*)d_ws;             // 1 MB each
  ushort* qlo   = qhi + 524288;
  ushort* khi   = qlo + 524288;
  ushort* klo   = khi + 524288;
  ushort* wqthi = klo + 524288;              // 2 MB each
  ushort* wqtlo = wqthi + 1048576;
  ushort* wkthi = wqtlo + 1048576;
  ushort* wktlo = wkthi + 1048576;
  float*  GQ    = (float*)(wktlo + 1048576); // [512][1024] f32 (2 MB)
  float*  GK    = GQ + 524288;               // [512][1024] f32 (2 MB)

  prep<<<dim3(1536), 256, 0, stream>>>(query, keys, Wq, Wk,
                                       qhi, qlo, khi, klo,
                                       wqthi, wqtlo, wkthi, wktlo);
  gemm_mfma<<<dim3(128, 2), 256, 0, stream>>>(qhi, qlo, khi, klo,
                                              wqthi, wqtlo, wkthi, wktlo, GQ, GK);
  attn_fused<<<dim3(1024), 512, 0, stream>>>(GQ, GK, Va, mask, values, weights, ctx);
}

// Round 21
// 62.967 us; speedup vs baseline: 1.0409x; 1.0280x over previous
//
#include <hip/hip_runtime.h>
#include <hip/hip_bf16.h>

// MultiHeadAttention (additive/Bahdanau): B=2, Q=K=256, HIDDEN=1024, 8 heads x 128
// Pipeline:
//  1) prep:      split query/keys -> bf16 hi/lo; W^T*2log2e -> bf16 hi/lo (LDS transpose)
//  2) gemm_mfma: 3-term bf16 MFMA GEMMs; epilogue stores g = 2^(clamp(a,+-480)/4) (f32):
//                GQ [512][1024], GK [512][1024] (both [row][d]; per-lane contiguous loads).
//  3) attn_fused (1024 blocks x 512 thr, q-tile 4): u = gq*gk; fminf(u,15); t = u^4.
//     8-way paired reciprocal: one rcp per 8 elements (den8 <= 4.3e37 finite).
//     R20 CHANGE: gq + Va read DIRECTLY from global with wave-uniform addresses ->
//     compiler emits s_load (SMEM, scalar pipe) -> zero VALU/LDS issue slots, no
//     lgkmcnt stalls (R13-R19 used LDS broadcast reads; 5 unexplained inst/elem).
//     Waves: d-halves x k-quarters; d-partials via LDS; softmax waves 0-3; PV
//     row-pairs x k-quarters over 8 waves. launch_bounds(512,4): no spills.

#define TANH_SCALE 2.88539008177792681472f   // 2*log2(e)
#define LOG2E      1.44269504088896340736f
#define UCLAMP     15.0f                     // t <= 50625; den8 <= 4.3e37 < f32max

typedef __attribute__((ext_vector_type(8))) short bf16x8_t;   // 8 bf16 = 4 VGPRs
typedef __attribute__((ext_vector_type(4))) float f32x4_t;

__device__ inline ushort bf16_rne(float f) {
  unsigned u = __float_as_uint(f);
  u += 0x7FFFu + ((u >> 16) & 1u);
  return (ushort)(u >> 16);
}
__device__ inline float bf16_to_f(ushort h) { return __uint_as_float((unsigned)h << 16); }
__device__ inline void split1(float v, ushort& hi, ushort& lo) {
  hi = bf16_rne(v);
  lo = bf16_rne(v - bf16_to_f(hi));
}

// ---------------- Kernel 1: prep (unchanged) ----------------
__global__ __launch_bounds__(256) void prep(
    const float* __restrict__ query, const float* __restrict__ keys,
    const float* __restrict__ Wq, const float* __restrict__ Wk,
    ushort* __restrict__ qhi, ushort* __restrict__ qlo,
    ushort* __restrict__ khi, ushort* __restrict__ klo,
    ushort* __restrict__ wqthi, ushort* __restrict__ wqtlo,
    ushort* __restrict__ wkthi, ushort* __restrict__ wktlo)
{
  __shared__ float t[64][65];
  const int bid = blockIdx.x, tid = threadIdx.x;
  if (bid < 1024) {
    const int z = bid >> 9;
    const float* in = z ? keys : query;
    ushort* hi = z ? khi : qhi;
    ushort* lo = z ? klo : qlo;
    const size_t i = ((size_t)(bid & 511) * 256 + tid) * 4;
    float4 v = *(const float4*)(in + i);
    ushort h0, h1, h2, h3, l0, l1, l2, l3;
    split1(v.x, h0, l0); split1(v.y, h1, l1);
    split1(v.z, h2, l2); split1(v.w, h3, l3);
    *(ushort4*)(hi + i) = make_ushort4(h0, h1, h2, h3);
    *(ushort4*)(lo + i) = make_ushort4(l0, l1, l2, l3);
  } else {
    const int idx = bid - 1024;
    const int z = idx >> 8;
    const float* W = z ? Wk : Wq;
    ushort* thi = z ? wkthi : wqthi;
    ushort* tlo = z ? wktlo : wqtlo;
    const int n0 = (idx & 15) * 64, h0 = ((idx >> 4) & 15) * 64;
    const int r = tid >> 4, c = (tid & 15) * 4;
#pragma unroll
    for (int i = 0; i < 4; ++i) {
      const int rr = r + i * 16;
      float4 wv = *(const float4*)(W + (size_t)(h0 + rr) * 1024 + n0 + c);
      t[rr][c + 0] = wv.x; t[rr][c + 1] = wv.y;
      t[rr][c + 2] = wv.z; t[rr][c + 3] = wv.w;
    }
    __syncthreads();
#pragma unroll
    for (int i = 0; i < 4; ++i) {
      const int rr = r + i * 16;
      ushort h0v, h1v, h2v, h3v, l0v, l1v, l2v, l3v;
      split1(t[c + 0][rr] * TANH_SCALE, h0v, l0v);
      split1(t[c + 1][rr] * TANH_SCALE, h1v, l1v);
      split1(t[c + 2][rr] * TANH_SCALE, h2v, l2v);
      split1(t[c + 3][rr] * TANH_SCALE, h3v, l3v);
      *(ushort4*)(thi + (size_t)(n0 + rr) * 1024 + h0 + c) = make_ushort4(h0v, h1v, h2v, h3v);
      *(ushort4*)(tlo + (size_t)(n0 + rr) * 1024 + h0 + c) = make_ushort4(l0v, l1v, l2v, l3v);
    }
  }
}

// ---------------- Kernel 2: MFMA GEMM, 3-term bf16 split; g = 2^(a/4) epilogue ----------------
// z=0: GQ = query@WqT; z=1: GK = keys@WkT. Identical geometry: [512][1024].
__global__ __launch_bounds__(256) void gemm_mfma(
    const ushort* __restrict__ qhi, const ushort* __restrict__ qlo,
    const ushort* __restrict__ khi, const ushort* __restrict__ klo,
    const ushort* __restrict__ wqthi, const ushort* __restrict__ wqtlo,
    const ushort* __restrict__ wkthi, const ushort* __restrict__ wktlo,
    float* __restrict__ GQ, float* __restrict__ GK)
{
  const int z = blockIdx.y;
  const int bid = blockIdx.x;
  const int m0 = (bid >> 4) * 64, n0 = (bid & 15) * 64;
  const ushort* Ah_g = z ? khi : qhi;
  const ushort* Al_g = z ? klo : qlo;
  const ushort* Bh_g = z ? wkthi : wqthi;
  const ushort* Bl_g = z ? wktlo : wqtlo;
  float* Gp = z ? GK : GQ;

  __shared__ __align__(16) ushort Ah[64 * 40];
  __shared__ __align__(16) ushort Al[64 * 40];
  __shared__ __align__(16) ushort Bh[64 * 40];
  __shared__ __align__(16) ushort Bl[64 * 40];

  const int tid = threadIdx.x;
  const int srow = tid >> 2, skc = (tid & 3) * 8;
  const size_t gA = (size_t)(m0 + srow) * 1024 + skc;
  const size_t gB = (size_t)(n0 + srow) * 1024 + skc;
  const int soff = srow * 40 + skc;

  uint4 rah = *(const uint4*)(Ah_g + gA);
  uint4 ral = *(const uint4*)(Al_g + gA);
  uint4 rbh = *(const uint4*)(Bh_g + gB);
  uint4 rbl = *(const uint4*)(Bl_g + gB);

  const int w = __builtin_amdgcn_readfirstlane(tid >> 6);
  const int lane = tid & 63;
  const int wm = (w >> 1) * 32, wn = (w & 1) * 32;
  const int fr = lane & 15, kg = lane >> 4;
  const int aoff = (wm + fr) * 40 + kg * 8;
  const int boff = (wn + fr) * 40 + kg * 8;

  f32x4_t acc[2][2] = {};

  for (int kk = 0; kk < 1024; kk += 32) {
    __syncthreads();
    *(uint4*)(Ah + soff) = rah;
    *(uint4*)(Al + soff) = ral;
    *(uint4*)(Bh + soff) = rbh;
    *(uint4*)(Bl + soff) = rbl;
    __syncthreads();

    if (kk + 32 < 1024) {
      rah = *(const uint4*)(Ah_g + gA + kk + 32);
      ral = *(const uint4*)(Al_g + gA + kk + 32);
      rbh = *(const uint4*)(Bh_g + gB + kk + 32);
      rbl = *(const uint4*)(Bl_g + gB + kk + 32);
    }

    bf16x8_t ah0 = *(const bf16x8_t*)(Ah + aoff);
    bf16x8_t ah1 = *(const bf16x8_t*)(Ah + aoff + 16 * 40);
    bf16x8_t al0 = *(const bf16x8_t*)(Al + aoff);
    bf16x8_t al1 = *(const bf16x8_t*)(Al + aoff + 16 * 40);
    bf16x8_t bh0 = *(const bf16x8_t*)(Bh + boff);
    bf16x8_t bh1 = *(const bf16x8_t*)(Bh + boff + 16 * 40);
    bf16x8_t bl0 = *(const bf16x8_t*)(Bl + boff);
    bf16x8_t bl1 = *(const bf16x8_t*)(Bl + boff + 16 * 40);

    acc[0][0] = __builtin_amdgcn_mfma_f32_16x16x32_bf16(ah0, bh0, acc[0][0], 0, 0, 0);
    acc[0][1] = __builtin_amdgcn_mfma_f32_16x16x32_bf16(ah0, bh1, acc[0][1], 0, 0, 0);
    acc[1][0] = __builtin_amdgcn_mfma_f32_16x16x32_bf16(ah1, bh0, acc[1][0], 0, 0, 0);
    acc[1][1] = __builtin_amdgcn_mfma_f32_16x16x32_bf16(ah1, bh1, acc[1][1], 0, 0, 0);
    acc[0][0] = __builtin_amdgcn_mfma_f32_16x16x32_bf16(ah0, bl0, acc[0][0], 0, 0, 0);
    acc[0][1] = __builtin_amdgcn_mfma_f32_16x16x32_bf16(ah0, bl1, acc[0][1], 0, 0, 0);
    acc[1][0] = __builtin_amdgcn_mfma_f32_16x16x32_bf16(ah1, bl0, acc[1][0], 0, 0, 0);
    acc[1][1] = __builtin_amdgcn_mfma_f32_16x16x32_bf16(ah1, bl1, acc[1][1], 0, 0, 0);
    acc[0][0] = __builtin_amdgcn_mfma_f32_16x16x32_bf16(al0, bh0, acc[0][0], 0, 0, 0);
    acc[0][1] = __builtin_amdgcn_mfma_f32_16x16x32_bf16(al0, bh1, acc[0][1], 0, 0, 0);
    acc[1][0] = __builtin_amdgcn_mfma_f32_16x16x32_bf16(al1, bh0, acc[1][0], 0, 0, 0);
    acc[1][1] = __builtin_amdgcn_mfma_f32_16x16x32_bf16(al1, bh1, acc[1][1], 0, 0, 0);
  }

#pragma unroll
  for (int fm = 0; fm < 2; ++fm)
#pragma unroll
    for (int fn = 0; fn < 2; ++fn) {
      const int col = n0 + wn + fn * 16 + fr;
#pragma unroll
      for (int j = 0; j < 4; ++j) {
        const int row = m0 + wm + fm * 16 + kg * 4 + j;
        float a = acc[fm][fn][j];
        a = fminf(fmaxf(a, -480.0f), 480.0f);
        Gp[(size_t)row * 1024 + col] = __builtin_amdgcn_exp2f(a * 0.25f);
      }
    }
}

// ---------------- Kernel 3: fused attn, scalar-pipe uniforms, 8-way paired rcp ----------------
// block = (b,h) = bid>>6, q-tile = (bid&63)*4. Wave w: d-half dh=w>>2, k-quarter kq=w&3,
// lane k = kq*64+lane. gq/Va loads are wave-uniform -> s_load (scalar pipe, free slots).
__global__ __launch_bounds__(512, 4) void attn_fused(
    const float* __restrict__ GQ, const float* __restrict__ GK,
    const float* __restrict__ Va, const int* __restrict__ mask,
    const float* __restrict__ values,
    float* __restrict__ weights, float* __restrict__ ctx)
{
  __shared__ __align__(16) float acc_lds[4][64][4];
  __shared__ float red_m[4][4];
  __shared__ float red_s[4][4];
  __shared__ __align__(16) float P_lds[4][256];
  __shared__ __align__(16) float4 pv_part[4][2][2][32];

  const int tid = threadIdx.x;
  const int lane = tid & 63;
  const int w = __builtin_amdgcn_readfirstlane(tid >> 6);
  const int bid = blockIdx.x;
  const int bh = bid >> 6;
  const int b = bh & 1, h = bh >> 1;
  const int qt = (bid & 63) * 4;
  const int dh = w >> 2, kq = w & 3;
  const int k = kq * 64 + lane;

  const float pen = 99.0f * (1.0f - (float)mask[b * 256 + k]);

  float ssum = Va[h * 128 + lane] + Va[h * 128 + 64 + lane];
#pragma unroll
  for (int off = 32; off; off >>= 1) ssum += __shfl_xor(ssum, off, 64);

  // per-lane contiguous gk row: [k][d] layout
  const float* gkp = GK + (size_t)(b * 256 + k) * 1024 + h * 128 + dh * 64;
  // wave-uniform bases (scalar loads)
  const float* gqp = GQ + (size_t)(b * 256 + qt) * 1024 + h * 128 + dh * 64;
  const float* vap = Va + h * 128 + dh * 64;

  float acc[4] = {0.f, 0.f, 0.f, 0.f};

  float4 gkcA = *(const float4*)(gkp + 0);
  float4 gkcB = *(const float4*)(gkp + 4);

  for (int ch = 0; ch < 8; ++ch) {      // 8 chunks x 8 d = 64 d per wave
    const int d0 = ch * 8;
    float4 gknA, gknB;
    if (ch < 7) {                       // prefetch next chunk: 2 contiguous dwordx4
      gknA = *(const float4*)(gkp + d0 + 8);
      gknB = *(const float4*)(gkp + d0 + 12);
    }
    // wave-uniform Va chunk (s_load)
    float va_[8];
    *(float4*)&va_[0] = *(const float4*)(vap + d0);
    *(float4*)&va_[4] = *(const float4*)(vap + d0 + 4);
    const float s01 = va_[0] + va_[1], s23 = va_[2] + va_[3];
    const float s45 = va_[4] + va_[5], s67 = va_[6] + va_[7];
#pragma unroll
    for (int q = 0; q < 4; ++q) {
      // wave-uniform gq chunk (s_load, immediate offsets)
      float4 A = *(const float4*)(gqp + (size_t)q * 1024 + d0);
      float4 Bv = *(const float4*)(gqp + (size_t)q * 1024 + d0 + 4);
      // quad A: d0..d3 -> NA/denA
      float u0 = fminf(A.x * gkcA.x, UCLAMP);
      float u1 = fminf(A.y * gkcA.y, UCLAMP);
      float u2 = fminf(A.z * gkcA.z, UCLAMP);
      float u3 = fminf(A.w * gkcA.w, UCLAMP);
      u0 *= u0; u1 *= u1; u2 *= u2; u3 *= u3;
      float t0 = u0 * u0, t1 = u1 * u1, t2 = u2 * u2, t3 = u3 * u3;
      float p01 = fmaf(t0, t1, t0 + t1 + 1.0f);
      float p23 = fmaf(t2, t3, t2 + t3 + 1.0f);
      const float denA = p01 * p23;
      float n01 = fmaf(va_[0], t1, fmaf(va_[1], t0, s01));
      float n23 = fmaf(va_[2], t3, fmaf(va_[3], t2, s23));
      const float NA = fmaf(n01, p23, n23 * p01);
      // quad B: d4..d7 -> NB/denB
      u0 = fminf(Bv.x * gkcB.x, UCLAMP);
      u1 = fminf(Bv.y * gkcB.y, UCLAMP);
      u2 = fminf(Bv.z * gkcB.z, UCLAMP);
      u3 = fminf(Bv.w * gkcB.w, UCLAMP);
      u0 *= u0; u1 *= u1; u2 *= u2; u3 *= u3;
      t0 = u0 * u0; t1 = u1 * u1; t2 = u2 * u2; t3 = u3 * u3;
      p01 = fmaf(t0, t1, t0 + t1 + 1.0f);
      p23 = fmaf(t2, t3, t2 + t3 + 1.0f);
      const float denB = p01 * p23;
      n01 = fmaf(va_[4], t1, fmaf(va_[5], t0, s45));
      n23 = fmaf(va_[6], t3, fmaf(va_[7], t2, s67));
      const float NB = fmaf(n01, p23, n23 * p01);
      // 8-way combine: one rcp
      const float den8 = denA * denB;                 // <= 4.3e37, finite
      const float N8 = fmaf(NA, denB, NB * denA);
      acc[q] = fmaf(N8, __builtin_amdgcn_rcpf(den8), acc[q]);
    }
    if (ch < 7) { gkcA = gknA; gkcB = gknB; }
  }

  // combine d-halves: waves 4-7 export, waves 0-3 absorb
  if (w >= 4) {
#pragma unroll
    for (int q = 0; q < 4; ++q) acc_lds[kq][lane][q] = acc[q];
  }
  __syncthreads();

  float l[4], p[4];
  if (w < 4) {
#pragma unroll
    for (int q = 0; q < 4; ++q) {
      acc[q] += acc_lds[kq][lane][q];
      l[q] = ssum - 2.0f * acc[q] - pen;
    }
#pragma unroll
    for (int q = 0; q < 4; ++q) {
      float m = l[q];
#pragma unroll
      for (int off = 32; off; off >>= 1) m = fmaxf(m, __shfl_xor(m, off, 64));
      if (lane == 0) red_m[w][q] = m;
    }
  }
  __syncthreads();
  if (w < 4) {
#pragma unroll
    for (int q = 0; q < 4; ++q) {
      float m = fmaxf(fmaxf(red_m[0][q], red_m[1][q]), fmaxf(red_m[2][q], red_m[3][q]));
      p[q] = __builtin_amdgcn_exp2f((l[q] - m) * LOG2E);
    }
#pragma unroll
    for (int q = 0; q < 4; ++q) {
      float s = p[q];
#pragma unroll
      for (int off = 32; off; off >>= 1) s += __shfl_xor(s, off, 64);
      if (lane == 0) red_s[w][q] = s;
    }
  }
  __syncthreads();
  if (w < 4) {
#pragma unroll
    for (int q = 0; q < 4; ++q) {
      const float s = (red_s[0][q] + red_s[1][q]) + (red_s[2][q] + red_s[3][q]);
      const float pq = p[q] / s;
      weights[((size_t)((b * 8 + h) * 256) + qt + q) * 256 + k] = pq;
      P_lds[q][k] = pq;
    }
  }
  __syncthreads();

  // PV: wave w -> row pair rp = w&1 (rows 2rp, 2rp+1), k-quarter kq2 = w>>1.
  {
    const int rp = w & 1, kq2 = w >> 1;
    const int d4 = lane & 31, ks = lane >> 5;
    const int q0 = rp * 2, q1 = q0 + 1;
    const float* vb =
        values + (size_t)(b * 256 + kq2 * 64 + ks * 32) * 1024 + h * 128 + d4 * 4;
    const float* w0p = &P_lds[q0][kq2 * 64 + ks * 32];
    const float* w1p = &P_lds[q1][kq2 * 64 + ks * 32];
    float4 A0 = make_float4(0, 0, 0, 0), A1 = make_float4(0, 0, 0, 0);
#pragma unroll 4
    for (int j = 0; j < 32; ++j) {
      float4 v = *(const float4*)(vb + (size_t)j * 1024);
      const float pw0 = w0p[j], pw1 = w1p[j];
      A0.x += pw0 * v.x; A0.y += pw0 * v.y; A0.z += pw0 * v.z; A0.w += pw0 * v.w;
      A1.x += pw1 * v.x; A1.y += pw1 * v.y; A1.z += pw1 * v.z; A1.w += pw1 * v.w;
    }
    A0.x += __shfl_xor(A0.x, 32, 64); A0.y += __shfl_xor(A0.y, 32, 64);
    A0.z += __shfl_xor(A0.z, 32, 64); A0.w += __shfl_xor(A0.w, 32, 64);
    A1.x += __shfl_xor(A1.x, 32, 64); A1.y += __shfl_xor(A1.y, 32, 64);
    A1.z += __shfl_xor(A1.z, 32, 64); A1.w += __shfl_xor(A1.w, 32, 64);
    if (kq2 != 0 && lane < 32) {
      pv_part[kq2][rp][0][d4] = A0;
      pv_part[kq2][rp][1][d4] = A1;
    }
    __syncthreads();
    if (kq2 == 0 && lane < 32) {
#pragma unroll
      for (int s = 1; s < 4; ++s) {
        float4 pa = pv_part[s][rp][0][d4];
        float4 pb = pv_part[s][rp][1][d4];
        A0.x += pa.x; A0.y += pa.y; A0.z += pa.z; A0.w += pa.w;
        A1.x += pb.x; A1.y += pb.y; A1.z += pb.z; A1.w += pb.w;
      }
      *(float4*)&ctx[(size_t)(b * 256 + qt + q0) * 1024 + h * 128 + d4 * 4] = A0;
      *(float4*)&ctx[(size_t)(b * 256 + qt + q1) * 1024 + h * 128 + d4 * 4] = A1;
    }
  }
}

extern "C" void kernel_launch(void* const* d_in, const int* in_sizes, int n_in,
                              void* d_out, int out_size, void* d_ws, size_t ws_size,
                              hipStream_t stream) {
  const float* query  = (const float*)d_in[0];
  const float* keys   = (const float*)d_in[1];
  const float* values = (const float*)d_in[2];
  const int*   mask   = (const int*)d_in[3];
  const float* Wq     = (const float*)d_in[4];
  const float* Wk     = (const float*)d_in[5];
  const float* Va     = (const float*)d_in[6];

  float* ctx     = (float*)d_out;            // [2,256,1024]
  float* weights = ctx + 524288;             // [2,8,256,256]

  // ws layout (~16 MB used):
  ushort* qhi   = (ushort*)d_ws;             // 1 MB each
  ushort* qlo   = qhi + 524288;
  ushort* khi   = qlo + 524288;
  ushort* klo   = khi + 524288;
  ushort* wqthi = klo + 524288;              // 2 MB each
  ushort* wqtlo = wqthi + 1048576;
  ushort* wkthi = wqtlo + 1048576;
  ushort* wktlo = wkthi + 1048576;
  float*  GQ    = (float*)(wktlo + 1048576); // [512][1024] f32 (2 MB)
  float*  GK    = GQ + 524288;               // [512][1024] f32 (2 MB)

  prep<<<dim3(1536), 256, 0, stream>>>(query, keys, Wq, Wk,
                                       qhi, qlo, khi, klo,
                                       wqthi, wqtlo, wkthi, wktlo);
  gemm_mfma<<<dim3(128, 2), 256, 0, stream>>>(qhi, qlo, khi, klo,
                                              wqthi, wqtlo, wkthi, wktlo, GQ, GK);
  attn_fused<<<dim3(1024), 512, 0, stream>>>(GQ, GK, Va, mask, values, weights, ctx);
}